// Round 4
// baseline (3233.508 us; speedup 1.0000x reference)
//
#include <hip/hip_runtime.h>
#include <math.h>

// Dims: B=8, NS=32, L=128, H=768, LH=256, C=4. N_SEQ=256, gates=1024.

typedef __bf16 bf16x8 __attribute__((ext_vector_type(8)));
typedef float  f32x4  __attribute__((ext_vector_type(4)));

__device__ __forceinline__ float sigmoidf_(float x){ return 1.0f/(1.0f+expf(-x)); }
__device__ __forceinline__ float fsig(float x){
    return __builtin_amdgcn_rcpf(1.0f + __expf(-x));
}
__device__ __forceinline__ float ftanh(float x){
    float a = fabsf(x);
    float e = __expf(-2.0f*a);
    float t = (1.0f - e) * __builtin_amdgcn_rcpf(1.0f + e);
    return copysignf(t, x);
}
__device__ __forceinline__ unsigned short f2bf(float x){
    unsigned int b = __float_as_uint(x);
    b += 0x7FFFu + ((b>>16)&1u);
    return (unsigned short)(b>>16);
}
__device__ __forceinline__ float bf2f(unsigned short h){
    return __uint_as_float(((unsigned int)h)<<16);
}
__device__ __forceinline__ void split_bf(float x, unsigned short &hi, unsigned short &lo){
    hi = f2bf(x);
    lo = f2bf(x - bf2f(hi));
}
__device__ __forceinline__ uint4 pack8(const unsigned short* s){
    uint4 u;
    u.x = (unsigned)s[0] | ((unsigned)s[1]<<16);
    u.y = (unsigned)s[2] | ((unsigned)s[3]<<16);
    u.z = (unsigned)s[4] | ((unsigned)s[5]<<16);
    u.w = (unsigned)s[6] | ((unsigned)s[7]<<16);
    return u;
}

// ---------------------------------------------------------------------------
__global__ void zero_f4(float4* __restrict__ p, int n) {
    int i = blockIdx.x * 256 + threadIdx.x;
    if (i < n) p[i] = make_float4(0.f, 0.f, 0.f, 0.f);
}

// ---------------------------------------------------------------------------
// X (32768x768 fp32) -> hi/lo bf16 frag-swizzled blocks.
// blk = mtile*24 + kb ; within blk: hi[ln*8+e] (512), lo at +512.
// element: m = mtile*16 + (ln&15), k = kb*32 + (ln>>4)*8 + e.
__global__ void prep_x(const float* __restrict__ X, unsigned short* __restrict__ Xsw) {
    int idx = blockIdx.x * 256 + threadIdx.x;   // 3,145,728 threads = 49152 blks x 64
    int gblk = idx >> 6, ln = idx & 63;
    int mt = gblk / 24, kb = gblk - mt * 24;
    int m = mt * 16 + (ln & 15);
    int k = kb * 32 + (ln >> 4) * 8;
    const float* xp = X + (size_t)m * 768 + k;
    unsigned short hi[8], lo[8];
#pragma unroll
    for (int e = 0; e < 8; e += 4) {
        float4 v = *(const float4*)(xp + e);
        split_bf(v.x, hi[e+0], lo[e+0]);
        split_bf(v.y, hi[e+1], lo[e+1]);
        split_bf(v.z, hi[e+2], lo[e+2]);
        split_bf(v.w, hi[e+3], lo[e+3]);
    }
    *(uint4*)&Xsw[(size_t)gblk*1024 + ln*8]       = pack8(hi);
    *(uint4*)&Xsw[(size_t)gblk*1024 + 512 + ln*8] = pack8(lo);
}

// ---------------------------------------------------------------------------
// W_ih (2 x [1024][768]) -> B-frag swizzled: blk = (dir*64+ntile)*24+kb.
// element: j = ntile*16 + (ln&15), k = kb*32 + (ln>>4)*8 + e.
__global__ void prep_wih_sw(const float* __restrict__ Wf, const float* __restrict__ Wb,
                            unsigned short* __restrict__ Wsw) {
    int idx = blockIdx.x * 256 + threadIdx.x;   // 196,608 = 3072 blks x 64
    int gblk = idx >> 6, ln = idx & 63;
    int dir = gblk / 1536;
    int rem = gblk - dir * 1536;
    int ntile = rem / 24, kb = rem - ntile * 24;
    int j = ntile * 16 + (ln & 15);
    int k = kb * 32 + (ln >> 4) * 8;
    const float* wp = (dir ? Wb : Wf) + (size_t)j * 768 + k;
    unsigned short hi[8], lo[8];
#pragma unroll
    for (int e = 0; e < 8; e += 4) {
        float4 v = *(const float4*)(wp + e);
        split_bf(v.x, hi[e+0], lo[e+0]);
        split_bf(v.y, hi[e+1], lo[e+1]);
        split_bf(v.z, hi[e+2], lo[e+2]);
        split_bf(v.w, hi[e+3], lo[e+3]);
    }
    *(uint4*)&Wsw[(size_t)gblk*1024 + ln*8]       = pack8(hi);
    *(uint4*)&Wsw[(size_t)gblk*1024 + 512 + ln*8] = pack8(lo);
}

// ---------------------------------------------------------------------------
// word W_hh (2 x [1024][256]) -> A-frag swizzled for word_rec streaming:
// blk = dir*512 + rt*8 + kb (rt 0..63, kb 0..7)
// element: gate row gr = (rt>>4)*256 + (rt&15)*16 + (ln&15), k = kb*32+(ln>>4)*8+e
__global__ void prep_whh_sw(const float* __restrict__ Wf, const float* __restrict__ Wb,
                            unsigned short* __restrict__ Wsw) {
    int idx = blockIdx.x * 256 + threadIdx.x;   // 65,536 = 1024 blks x 64
    int gblk = idx >> 6, ln = idx & 63;
    int dir = gblk >> 9;
    int rem = gblk & 511;
    int rt = rem >> 3, kb = rem & 7;
    int gr = (rt >> 4) * 256 + (rt & 15) * 16 + (ln & 15);
    int k = kb * 32 + (ln >> 4) * 8;
    const float* wp = (dir ? Wb : Wf) + (size_t)gr * 256 + k;
    unsigned short hi[8], lo[8];
#pragma unroll
    for (int e = 0; e < 8; e += 4) {
        float4 v = *(const float4*)(wp + e);
        split_bf(v.x, hi[e+0], lo[e+0]);
        split_bf(v.y, hi[e+1], lo[e+1]);
        split_bf(v.z, hi[e+2], lo[e+2]);
        split_bf(v.w, hi[e+3], lo[e+3]);
    }
    *(uint4*)&Wsw[(size_t)gblk*1024 + ln*8]       = pack8(hi);
    *(uint4*)&Wsw[(size_t)gblk*1024 + 512 + ln*8] = pack8(lo);
}

// ---------------------------------------------------------------------------
// transpose sentence-level W_hh (2 x [1024][256]) -> Wt[dir][k][j]
__global__ void transpose_whh(const float* __restrict__ Wf, const float* __restrict__ Wb,
                              float* __restrict__ Wt) {
    int idx = blockIdx.x * 256 + threadIdx.x;
    if (idx >= 524288) return;
    int dir = idx >> 18;
    int rem = idx & 262143;
    int k = rem >> 10;
    int j = rem & 1023;
    const float* Wp = dir ? Wb : Wf;
    Wt[idx] = Wp[j * 256 + k];
}

// ---------------------------------------------------------------------------
// Word input projection, split-bf16 MFMA, m97-style global_load_lds staging.
// BM=256 (16 mtiles), BN=128 (8 ntiles), BK=32. Output in word_rec's
// per-thread epilogue layout: off = t*262144 + sg*16384 + chunk*64 + jhi*16+g*4+r.
__global__ __launch_bounds__(256, 2) void proj_mfma(
    const unsigned short* __restrict__ Xsw,
    const unsigned short* __restrict__ Wihsw,
    const float* __restrict__ bfw, const float* __restrict__ bbw,
    float* __restrict__ Of, float* __restrict__ Ob)
{
    __shared__ unsigned short lds[24576];   // A: 16 blks x 1024 ; B at 16384: 8 blks
    const int tid = threadIdx.x;
    const int nt = blockIdx.x;      // 0..15
    const int mt = blockIdx.y;      // 0..127
    const int sel = nt >> 3;
    const int ntl = nt & 7;
    const float* bias = sel ? bbw : bfw;
    float* Op = sel ? Ob : Of;
    const int wv = tid >> 6, ln = tid & 63;
    const int c = ln & 15, q = ln >> 4;

    f32x4 acc[4][8];
#pragma unroll
    for (int i = 0; i < 4; i++)
#pragma unroll
        for (int j = 0; j < 8; j++) acc[i][j] = f32x4{0.f,0.f,0.f,0.f};

    const unsigned short* Abase = Xsw + (size_t)(mt*16) * 24 * 1024;
    const unsigned short* Bbase = Wihsw + (size_t)(sel*64 + ntl*8) * 24 * 1024;

#pragma unroll 1
    for (int kb = 0; kb < 24; kb++) {
        __syncthreads();
#pragma unroll
        for (int jj = 0; jj < 12; jj++) {
            int cc = wv + 4*jj;                  // 0..47, wave-uniform
            int isB = (cc >= 32);
            int blk = isB ? ((cc - 32) >> 1) : (cc >> 1);
            int half = cc & 1;
            const unsigned short* src = (isB ? Bbase : Abase)
                                        + (size_t)(blk*24 + kb)*1024 + half*512 + ln*8;
            unsigned short* dst = lds + (isB ? 16384 : 0) + blk*1024 + half*512 + ln*8;
            __builtin_amdgcn_global_load_lds(
                (const __attribute__((address_space(1))) unsigned int*)src,
                (__attribute__((address_space(3))) unsigned int*)dst, 16, 0, 0);
        }
        __syncthreads();

        bf16x8 bhv[8], blv[8];
#pragma unroll
        for (int cb = 0; cb < 8; cb++) {
            bhv[cb] = *(const bf16x8*)&lds[16384 + cb*1024 + ln*8];
            blv[cb] = *(const bf16x8*)&lds[16384 + cb*1024 + 512 + ln*8];
        }
#pragma unroll
        for (int rb = 0; rb < 4; rb++) {
            int it = wv*4 + rb;
            bf16x8 ah = *(const bf16x8*)&lds[it*1024 + ln*8];
            bf16x8 al = *(const bf16x8*)&lds[it*1024 + 512 + ln*8];
#pragma unroll
            for (int cb = 0; cb < 8; cb++) {
                acc[rb][cb] = __builtin_amdgcn_mfma_f32_16x16x32_bf16(ah, bhv[cb], acc[rb][cb], 0,0,0);
                acc[rb][cb] = __builtin_amdgcn_mfma_f32_16x16x32_bf16(ah, blv[cb], acc[rb][cb], 0,0,0);
                acc[rb][cb] = __builtin_amdgcn_mfma_f32_16x16x32_bf16(al, bhv[cb], acc[rb][cb], 0,0,0);
            }
        }
    }

    // epilogue: D row (within mtile) = q*4+reg, col j = ntl*128 + cb*16 + c
#pragma unroll
    for (int rb = 0; rb < 4; rb++) {
        int mbase = (mt*16 + wv*4 + rb)*16 + q*4;
#pragma unroll
        for (int cb = 0; cb < 8; cb++) {
            int j = ntl*128 + cb*16 + c;
            float bv = bias[j];
            int g = j >> 8, u = j & 255;
            int wvw = (u >> 4) & 3, jhi = u >> 6, qw = (u >> 2) & 3, r = u & 3;
            int inner = ((wvw*4 + qw)*16)*64 + jhi*16 + g*4 + r;
#pragma unroll
            for (int reg = 0; reg < 4; reg++) {
                int m = mbase + reg;
                int tt = m & 127, nn = m >> 7;
                int sg = nn >> 4, ccn = nn & 15;
                Op[(size_t)tt*262144 + sg*16384 + ccn*64 + inner] = acc[rb][cb][reg] + bv;
            }
        }
    }
}

// ---------------------------------------------------------------------------
// Persistent word BiLSTM: 32 independent WGs = dir(2) x seq-group(16 of 16 seqs).
// All 128 steps WG-local: h in LDS (bf16 hi/lo B-frags), c & pooled-sums in
// registers, W_hh streamed global->VGPR as pre-swizzled A-frags (L2-resident,
// 16-way broadcast reuse). No cross-WG sync of any kind.
__global__ void __launch_bounds__(256, 1) word_rec(
    const float* __restrict__ Gf, const float* __restrict__ Gb,
    const unsigned short* __restrict__ Whhsw,
    const int* __restrict__ mask,
    float* __restrict__ pooled)
{
    __shared__ unsigned short Hs[8448];   // hi: [c*264+u] (4224), lo at +4224
    const int tid = threadIdx.x, bid = blockIdx.x;
    const int dir = bid >> 4, sg = bid & 15;
    const int wv = tid >> 6, ln = tid & 63;
    const int c = ln & 15, q = ln >> 4;
    const float* G = dir ? Gb : Gf;
    const unsigned short* Wd = Whhsw + dir*524288 + wv*8192 + ln*8;
    const int nseq = sg*16 + c;

    for (int i = tid; i < 4224; i += 256) ((unsigned int*)Hs)[i] = 0u;

    float c_reg[16], ps[16];
#pragma unroll
    for (int i = 0; i < 16; i++) { c_reg[i] = 0.f; ps[i] = 0.f; }
    int cnt = 0;
    __syncthreads();

#pragma unroll 1
    for (int t = 0; t < 128; t++) {
        const int te = dir ? (127 - t) : t;
        // G prefetch: this thread's 16 float4 (contiguous 256 B; wave = 16 KB)
        const f32x4* gp = (const f32x4*)(G + (size_t)te*262144 + sg*16384
                                          + ((wv*4 + q)*16 + c)*64);
        f32x4 Greg[16];
#pragma unroll
        for (int jg = 0; jg < 16; jg++) Greg[jg] = gp[jg];
        const int mk = mask[nseq*128 + te];

        f32x4 acc[16];
#pragma unroll
        for (int j = 0; j < 16; j++) acc[j] = f32x4{0.f,0.f,0.f,0.f};

#pragma unroll 2
        for (int kb = 0; kb < 8; kb++) {
            bf16x8 bh = *(const bf16x8*)&Hs[c*264 + kb*32 + q*8];
            bf16x8 bl = *(const bf16x8*)&Hs[4224 + c*264 + kb*32 + q*8];
            const unsigned short* wp = Wd + kb*1024;
#pragma unroll
            for (int j = 0; j < 16; j++) {
                bf16x8 wh = *(const bf16x8*)(wp + j*32768);
                bf16x8 wl = *(const bf16x8*)(wp + j*32768 + 512);
                acc[j] = __builtin_amdgcn_mfma_f32_16x16x32_bf16(wh, bh, acc[j], 0,0,0);
                acc[j] = __builtin_amdgcn_mfma_f32_16x16x32_bf16(wh, bl, acc[j], 0,0,0);
                acc[j] = __builtin_amdgcn_mfma_f32_16x16x32_bf16(wl, bh, acc[j], 0,0,0);
            }
        }
        __syncthreads();   // all Hs B-frag reads done

        // epilogue fully in-register: thread owns units u=(4*jhi+wv)*16+q*4+r, seq c
#pragma unroll
        for (int jhi = 0; jhi < 4; jhi++) {
            unsigned short hh[4], hl[4];
#pragma unroll
            for (int r = 0; r < 4; r++) {
                float iv = acc[jhi][r]       + Greg[jhi*4 + 0][r];
                float fv = acc[4 + jhi][r]   + Greg[jhi*4 + 1][r];
                float gv = acc[8 + jhi][r]   + Greg[jhi*4 + 2][r];
                float ov = acc[12 + jhi][r]  + Greg[jhi*4 + 3][r];
                float cr = c_reg[jhi*4 + r];
                float cn = fsig(fv)*cr + fsig(iv)*ftanh(gv);
                float hn = fsig(ov)*ftanh(cn);
                c_reg[jhi*4 + r] = cn;
                if (mk) ps[jhi*4 + r] += hn;
                split_bf(hn, hh[r], hl[r]);
            }
            const int ub = (4*jhi + wv)*16 + q*4;
            ushort4 vh; vh.x = hh[0]; vh.y = hh[1]; vh.z = hh[2]; vh.w = hh[3];
            ushort4 vl; vl.x = hl[0]; vl.y = hl[1]; vl.z = hl[2]; vl.w = hl[3];
            *(ushort4*)&Hs[c*264 + ub] = vh;
            *(ushort4*)&Hs[4224 + c*264 + ub] = vl;
        }
        cnt += (mk ? 1 : 0);
        __syncthreads();
    }

    const float inv = 1.0f / fmaxf((float)cnt, 1.0f);
#pragma unroll
    for (int jhi = 0; jhi < 4; jhi++)
#pragma unroll
        for (int r = 0; r < 4; r++) {
            int u = (4*jhi + wv)*16 + q*4 + r;
            pooled[nseq*512 + dir*256 + u] = ps[jhi*4 + r] * inv;
        }
}

// ---------------------------------------------------------------------------
// fp32 input-projection GEMM (sentence level), plain layout out.
__global__ __launch_bounds__(256) void gemm_proj(
    const float* __restrict__ A, int M, int K,
    const float* __restrict__ Wf, const float* __restrict__ Wb,
    const float* __restrict__ bf, const float* __restrict__ bb,
    float* __restrict__ Of, float* __restrict__ Ob)
{
    __shared__ float As[16][132];
    __shared__ float Bs[16][132];
    const int t = threadIdx.x;
    const int n0 = blockIdx.x * 128;
    const int m0 = blockIdx.y * 128;
    const int sel = (n0 >= 1024);
    const float* Wp = sel ? Wb : Wf;
    const float* bp = sel ? bb : bf;
    float* Op = sel ? Ob : Of;
    const int n0d = n0 & 1023;
    const int tm = t >> 4;
    const int tn = t & 15;

    float acc[8][8];
#pragma unroll
    for (int i = 0; i < 8; i++)
#pragma unroll
        for (int j = 0; j < 8; j++) acc[i][j] = 0.f;

    for (int k0 = 0; k0 < K; k0 += 16) {
        __syncthreads();
#pragma unroll
        for (int rr = 0; rr < 2; rr++) {
            int idx = t + rr * 256;
            int row = idx >> 2, kq = idx & 3;
            float4 v = *(const float4*)&A[(size_t)(m0 + row) * K + k0 + kq * 4];
            As[kq*4+0][row] = v.x; As[kq*4+1][row] = v.y;
            As[kq*4+2][row] = v.z; As[kq*4+3][row] = v.w;
        }
#pragma unroll
        for (int rr = 0; rr < 2; rr++) {
            int idx = t + rr * 256;
            int row = idx >> 2, kq = idx & 3;
            float4 v = *(const float4*)&Wp[(size_t)(n0d + row) * K + k0 + kq * 4];
            Bs[kq*4+0][row] = v.x; Bs[kq*4+1][row] = v.y;
            Bs[kq*4+2][row] = v.z; Bs[kq*4+3][row] = v.w;
        }
        __syncthreads();
#pragma unroll
        for (int k = 0; k < 16; k++) {
            float4 a0 = *(const float4*)&As[k][tm*4];
            float4 a1 = *(const float4*)&As[k][tm*4+64];
            float4 b0 = *(const float4*)&Bs[k][tn*4];
            float4 b1 = *(const float4*)&Bs[k][tn*4+64];
            float av[8] = {a0.x,a0.y,a0.z,a0.w,a1.x,a1.y,a1.z,a1.w};
            float bv[8] = {b0.x,b0.y,b0.z,b0.w,b1.x,b1.y,b1.z,b1.w};
#pragma unroll
            for (int i = 0; i < 8; i++)
#pragma unroll
                for (int j = 0; j < 8; j++)
                    acc[i][j] += av[i] * bv[j];
        }
    }

#pragma unroll
    for (int ih = 0; ih < 2; ih++) {
#pragma unroll
        for (int i = 0; i < 4; i++) {
            int m = m0 + ih*64 + tm*4 + i;
#pragma unroll
            for (int jh = 0; jh < 2; jh++) {
                int col = n0d + jh*64 + tn*4;
                float4 bias4 = *(const float4*)&bp[col];
                float4 r;
                r.x = acc[ih*4+i][jh*4+0] + bias4.x;
                r.y = acc[ih*4+i][jh*4+1] + bias4.y;
                r.z = acc[ih*4+i][jh*4+2] + bias4.z;
                r.w = acc[ih*4+i][jh*4+3] + bias4.w;
                *(float4*)&Op[(size_t)m * 1024 + col] = r;
            }
        }
    }
}

// ---------------------------------------------------------------------------
__global__ __launch_bounds__(256) void sent_step(
    const float* __restrict__ Gsf, const float* __restrict__ Gsb,
    const float* __restrict__ Wt,
    const float* __restrict__ h_in, float* __restrict__ h_out,
    float* __restrict__ c_s, float* __restrict__ final_h, int s)
{
    __shared__ float h_lds[256];
    __shared__ float part[256];
    __shared__ float ex[4][33];
    const int tid = threadIdx.x;
    const int bx = blockIdx.x;
    const int dir = bx >> 6;
    const int rb = bx & 63;
    const int b = rb >> 3;
    const int ut = rb & 7;
    const int u0 = ut * 32;
    const int t_eff = dir ? (31 - s) : s;
    const float* Gs = dir ? Gsb : Gsf;

    if (tid < 64) {
        float4 v = *(const float4*)&h_in[dir*2048 + b*256 + tid*4];
        *(float4*)&h_lds[tid*4] = v;
    }
    __syncthreads();

    const int kh = tid >> 7;
    const int rr = tid & 127;
    const int g = rr >> 5;
    const int uu = rr & 31;
    const int j = g*256 + u0 + uu;
    const float* wp = Wt + dir*262144 + kh*128*1024 + j;
    float acc = 0.f;
#pragma unroll 8
    for (int k = 0; k < 128; k++)
        acc += wp[k*1024] * h_lds[kh*128 + k];
    part[tid] = acc;
    __syncthreads();
    if (tid < 128) ex[g][uu] = part[tid] + part[tid + 128];
    __syncthreads();

    if (tid < 32) {
        int u = u0 + tid;
        size_t gb = (size_t)(b*32 + t_eff)*1024 + u;
        float iv = ex[0][tid] + Gs[gb];
        float fv = ex[1][tid] + Gs[gb + 256];
        float gv = ex[2][tid] + Gs[gb + 512];
        float ov = ex[3][tid] + Gs[gb + 768];
        int ci = dir*2048 + b*256 + u;
        float cold = c_s[ci];
        float cn = sigmoidf_(fv)*cold + sigmoidf_(iv)*tanhf(gv);
        float hn = sigmoidf_(ov)*tanhf(cn);
        c_s[ci] = cn;
        h_out[ci] = hn;
        if (t_eff == 31) final_h[b*512 + dir*256 + u] = hn;
    }
}

// ---------------------------------------------------------------------------
__global__ __launch_bounds__(256) void logits_k(const float* __restrict__ fh,
                                                const float* __restrict__ cw,
                                                const float* __restrict__ cb,
                                                float* __restrict__ out) {
    __shared__ float red[256];
    int tid = threadIdx.x;
    int o = tid >> 3;
    int b = o >> 2; int c = o & 3;
    int pp = tid & 7;
    float acc = 0.f;
    const float* fv = fh + b*512 + pp*64;
    const float* wv = cw + c*512 + pp*64;
#pragma unroll 8
    for (int e = 0; e < 64; e++) acc += fv[e]*wv[e];
    red[tid] = acc;
    __syncthreads();
    if (pp == 0) {
        float s = 0.f;
#pragma unroll
        for (int qq = 0; qq < 8; qq++) s += red[o*8 + qq];
        out[o] = s + cb[c];
    }
}

// ---------------------------------------------------------------------------
extern "C" void kernel_launch(void* const* d_in, const int* in_sizes, int n_in,
                              void* d_out, int out_size, void* d_ws, size_t ws_size,
                              hipStream_t stream) {
    const float* X       = (const float*)d_in[0];
    const int*   mask    = (const int*)d_in[1];
    const float* wl_ih_f = (const float*)d_in[2];
    const float* wl_hh_f = (const float*)d_in[3];
    const float* wl_b_f  = (const float*)d_in[4];
    const float* wl_ih_b = (const float*)d_in[5];
    const float* wl_hh_b = (const float*)d_in[6];
    const float* wl_b_b  = (const float*)d_in[7];
    const float* ws_ih_f = (const float*)d_in[8];
    const float* ws_hh_f = (const float*)d_in[9];
    const float* ws_b_f  = (const float*)d_in[10];
    const float* ws_ih_b = (const float*)d_in[11];
    const float* ws_hh_b = (const float*)d_in[12];
    const float* ws_b_b  = (const float*)d_in[13];
    const float* cls_w   = (const float*)d_in[14];
    const float* cls_b   = (const float*)d_in[15];
    float* out = (float*)d_out;
    float* w = (float*)d_ws;
    (void)in_sizes; (void)n_in; (void)out_size; (void)ws_size;

    // workspace layout
    float* Gf     = w;                         // 33,554,432 (word_rec layout, dir f)
    float* Gb     = Gf + 33554432;             // 33,554,432
    float* Gsf    = Gb + 33554432;             // 262,144
    float* Gsb    = Gsf + 262144;              // 262,144
    float* Wt     = Gsb + 262144;              // 524,288
    float* finalh = Wt + 524288;               // 4,096
    float* pooled = finalh + 4096;             // 131,072 (fully overwritten)
    float* hs0    = pooled + 131072;           // 4,096 (zeroed)
    float* hs1    = hs0 + 4096;                // 4,096 (zeroed)
    float* cs     = hs1 + 4096;                // 4,096 (zeroed)
    unsigned short* Xsw   = (unsigned short*)(cs + 4096);   // 50,331,648 ushorts
    unsigned short* Wihsw = Xsw + 50331648;                 // 3,145,728
    unsigned short* Whhsw = Wihsw + 3145728;                // 1,048,576

    // zero hs0,hs1,cs = 12288 floats = 3072 float4
    zero_f4<<<12, 256, 0, stream>>>((float4*)hs0, 3072);
    prep_x<<<12288, 256, 0, stream>>>(X, Xsw);
    prep_wih_sw<<<768, 256, 0, stream>>>(wl_ih_f, wl_ih_b, Wihsw);
    prep_whh_sw<<<256, 256, 0, stream>>>(wl_hh_f, wl_hh_b, Whhsw);
    transpose_whh<<<2048, 256, 0, stream>>>(ws_hh_f, ws_hh_b, Wt);

    // word input projection (split-bf16 MFMA, word_rec-layout output)
    proj_mfma<<<dim3(16, 128), 256, 0, stream>>>(Xsw, Wihsw, wl_b_f, wl_b_b, Gf, Gb);

    // persistent word recurrence: 32 fully-independent WGs, one launch
    word_rec<<<32, 256, 0, stream>>>(Gf, Gb, Whhsw, mask, pooled);

    // sentence input projection (fp32): (256x512) @ (512x2048)
    gemm_proj<<<dim3(16, 2), 256, 0, stream>>>(pooled, 256, 512,
                                               ws_ih_f, ws_ih_b, ws_b_f, ws_b_b,
                                               Gsf, Gsb);

    for (int s = 0; s < 32; s++) {
        float* hin  = (s & 1) ? hs1 : hs0;
        float* hout = (s & 1) ? hs0 : hs1;
        sent_step<<<128, 256, 0, stream>>>(Gsf, Gsb, Wt, hin, hout, cs, finalh, s);
    }

    logits_k<<<1, 256, 0, stream>>>(finalh, cls_w, cls_b, out);
}

// Round 5
// 1382.938 us; speedup vs baseline: 2.3381x; 2.3381x over previous
//
#include <hip/hip_runtime.h>
#include <math.h>

// Dims: B=8, NS=32, L=128, H=768, LH=256, C=4. N_SEQ=256, gates=1024.

typedef __bf16 bf16x8 __attribute__((ext_vector_type(8)));
typedef float  f32x4  __attribute__((ext_vector_type(4)));

__device__ __forceinline__ float sigmoidf_(float x){ return 1.0f/(1.0f+expf(-x)); }
__device__ __forceinline__ unsigned short f2bf(float x){
    unsigned int b = __float_as_uint(x);
    b += 0x7FFFu + ((b>>16)&1u);
    return (unsigned short)(b>>16);
}
__device__ __forceinline__ float bf2f(unsigned short h){
    return __uint_as_float(((unsigned int)h)<<16);
}
__device__ __forceinline__ void split_bf(float x, unsigned short &hi, unsigned short &lo){
    hi = f2bf(x);
    lo = f2bf(x - bf2f(hi));
}
__device__ __forceinline__ uint4 pack8(const unsigned short* s){
    uint4 u;
    u.x = (unsigned)s[0] | ((unsigned)s[1]<<16);
    u.y = (unsigned)s[2] | ((unsigned)s[3]<<16);
    u.z = (unsigned)s[4] | ((unsigned)s[5]<<16);
    u.w = (unsigned)s[6] | ((unsigned)s[7]<<16);
    return u;
}

// ---------------------------------------------------------------------------
__global__ void zero_f4(float4* __restrict__ p, int n) {
    int i = blockIdx.x * 256 + threadIdx.x;
    if (i < n) p[i] = make_float4(0.f, 0.f, 0.f, 0.f);
}

// ---------------------------------------------------------------------------
// X (32768x768 fp32) -> hi/lo bf16 frag-swizzled blocks.
// blk = mtile*24 + kb ; within blk: hi[ln*8+e] (512), lo at +512.
// element: m = mtile*16 + (ln&15), k = kb*32 + (ln>>4)*8 + e.
__global__ void prep_x(const float* __restrict__ X, unsigned short* __restrict__ Xsw) {
    int idx = blockIdx.x * 256 + threadIdx.x;   // 3,145,728 threads = 49152 blks x 64
    int gblk = idx >> 6, ln = idx & 63;
    int mt = gblk / 24, kb = gblk - mt * 24;
    int m = mt * 16 + (ln & 15);
    int k = kb * 32 + (ln >> 4) * 8;
    const float* xp = X + (size_t)m * 768 + k;
    unsigned short hi[8], lo[8];
#pragma unroll
    for (int e = 0; e < 8; e += 4) {
        float4 v = *(const float4*)(xp + e);
        split_bf(v.x, hi[e+0], lo[e+0]);
        split_bf(v.y, hi[e+1], lo[e+1]);
        split_bf(v.z, hi[e+2], lo[e+2]);
        split_bf(v.w, hi[e+3], lo[e+3]);
    }
    *(uint4*)&Xsw[(size_t)gblk*1024 + ln*8]       = pack8(hi);
    *(uint4*)&Xsw[(size_t)gblk*1024 + 512 + ln*8] = pack8(lo);
}

// ---------------------------------------------------------------------------
// W_ih (2 x [1024][768]) -> B-frag swizzled: blk = (dir*64+ntile)*24+kb.
// element: j = ntile*16 + (ln&15), k = kb*32 + (ln>>4)*8 + e.
__global__ void prep_wih_sw(const float* __restrict__ Wf, const float* __restrict__ Wb,
                            unsigned short* __restrict__ Wsw) {
    int idx = blockIdx.x * 256 + threadIdx.x;   // 196,608 = 3072 blks x 64
    int gblk = idx >> 6, ln = idx & 63;
    int dir = gblk / 1536;
    int rem = gblk - dir * 1536;
    int ntile = rem / 24, kb = rem - ntile * 24;
    int j = ntile * 16 + (ln & 15);
    int k = kb * 32 + (ln >> 4) * 8;
    const float* wp = (dir ? Wb : Wf) + (size_t)j * 768 + k;
    unsigned short hi[8], lo[8];
#pragma unroll
    for (int e = 0; e < 8; e += 4) {
        float4 v = *(const float4*)(wp + e);
        split_bf(v.x, hi[e+0], lo[e+0]);
        split_bf(v.y, hi[e+1], lo[e+1]);
        split_bf(v.z, hi[e+2], lo[e+2]);
        split_bf(v.w, hi[e+3], lo[e+3]);
    }
    *(uint4*)&Wsw[(size_t)gblk*1024 + ln*8]       = pack8(hi);
    *(uint4*)&Wsw[(size_t)gblk*1024 + 512 + ln*8] = pack8(lo);
}

// ---------------------------------------------------------------------------
// Build word W_hh LDS images: per (dir, u0t of 16 tiles):
//   [hi: 4g x 16u x 264][lo: same], 34816 ushorts per image.
// Gate-row source: row = g*256 + u0t*16 + u, k = 0..255.
__global__ void prep_whh(const float* __restrict__ Wf, const float* __restrict__ Wb,
                         unsigned short* __restrict__ Wimg) {
    int idx = blockIdx.x * 256 + threadIdx.x;
    if (idx >= 524288) return;
    int dir = idx >> 18;
    int r   = idx & 262143;
    int u0t = r >> 14;
    int g   = (r >> 12) & 3;
    int u   = (r >> 8) & 15;
    int k   = r & 255;
    const float* W = dir ? Wb : Wf;
    float v = W[(size_t)(g*256 + u0t*16 + u) * 256 + k];
    unsigned short hi, lo; split_bf(v, hi, lo);
    size_t base = (size_t)(dir*16 + u0t) * 34816;
    Wimg[base + (g*16 + u)*264 + k]         = hi;
    Wimg[base + 16896 + (g*16 + u)*264 + k] = lo;
}

// ---------------------------------------------------------------------------
// transpose sentence-level W_hh (2 x [1024][256]) -> Wt[dir][k][j]
__global__ void transpose_whh(const float* __restrict__ Wf, const float* __restrict__ Wb,
                              float* __restrict__ Wt) {
    int idx = blockIdx.x * 256 + threadIdx.x;
    if (idx >= 524288) return;
    int dir = idx >> 18;
    int rem = idx & 262143;
    int k = rem >> 10;
    int j = rem & 1023;
    const float* Wp = dir ? Wb : Wf;
    Wt[idx] = Wp[j * 256 + k];
}

// ---------------------------------------------------------------------------
// Word input projection, split-bf16 MFMA, global_load_lds staging of
// pre-swizzled inputs; coalesced t-major epilogue:
//   G[t*256+n][j] = sum_k X[n*128+t][k]*W[j][k] + b[j]
// BM=256 (16 mtiles), BN=128 (8 ntiles), BK=32.
__global__ __launch_bounds__(256, 2) void proj_mfma(
    const unsigned short* __restrict__ Xsw,
    const unsigned short* __restrict__ Wihsw,
    const float* __restrict__ bfw, const float* __restrict__ bbw,
    float* __restrict__ Of, float* __restrict__ Ob)
{
    __shared__ unsigned short lds[24576];   // A: 16 blks x 1024 ; B at 16384: 8 blks
    const int tid = threadIdx.x;
    const int nt = blockIdx.x;      // 0..15
    const int mt = blockIdx.y;      // 0..127
    const int sel = nt >> 3;
    const int ntl = nt & 7;
    const float* bias = sel ? bbw : bfw;
    float* Op = sel ? Ob : Of;
    const int wv = tid >> 6, ln = tid & 63;
    const int c = ln & 15, q = ln >> 4;

    f32x4 acc[4][8];
#pragma unroll
    for (int i = 0; i < 4; i++)
#pragma unroll
        for (int j = 0; j < 8; j++) acc[i][j] = f32x4{0.f,0.f,0.f,0.f};

    const unsigned short* Abase = Xsw + (size_t)(mt*16) * 24 * 1024;
    const unsigned short* Bbase = Wihsw + (size_t)(sel*64 + ntl*8) * 24 * 1024;

#pragma unroll 1
    for (int kb = 0; kb < 24; kb++) {
        __syncthreads();
#pragma unroll
        for (int jj = 0; jj < 12; jj++) {
            int cc = wv + 4*jj;                  // 0..47, wave-uniform
            int isB = (cc >= 32);
            int blk = isB ? ((cc - 32) >> 1) : (cc >> 1);
            int half = cc & 1;
            const unsigned short* src = (isB ? Bbase : Abase)
                                        + (size_t)(blk*24 + kb)*1024 + half*512 + ln*8;
            unsigned short* dst = lds + (isB ? 16384 : 0) + blk*1024 + half*512 + ln*8;
            __builtin_amdgcn_global_load_lds(
                (const __attribute__((address_space(1))) unsigned int*)src,
                (__attribute__((address_space(3))) unsigned int*)dst, 16, 0, 0);
        }
        __syncthreads();

        bf16x8 bhv[8], blv[8];
#pragma unroll
        for (int cb = 0; cb < 8; cb++) {
            bhv[cb] = *(const bf16x8*)&lds[16384 + cb*1024 + ln*8];
            blv[cb] = *(const bf16x8*)&lds[16384 + cb*1024 + 512 + ln*8];
        }
#pragma unroll
        for (int rb = 0; rb < 4; rb++) {
            int it = wv*4 + rb;
            bf16x8 ah = *(const bf16x8*)&lds[it*1024 + ln*8];
            bf16x8 al = *(const bf16x8*)&lds[it*1024 + 512 + ln*8];
#pragma unroll
            for (int cb = 0; cb < 8; cb++) {
                acc[rb][cb] = __builtin_amdgcn_mfma_f32_16x16x32_bf16(ah, bhv[cb], acc[rb][cb], 0,0,0);
                acc[rb][cb] = __builtin_amdgcn_mfma_f32_16x16x32_bf16(ah, blv[cb], acc[rb][cb], 0,0,0);
                acc[rb][cb] = __builtin_amdgcn_mfma_f32_16x16x32_bf16(al, bhv[cb], acc[rb][cb], 0,0,0);
            }
        }
    }

    // epilogue: D row = q*4+reg within mtile, col j = ntl*128 + cb*16 + c.
    // Source row m -> (t=m&127, n=m>>7); store lane-contiguous in j.
#pragma unroll
    for (int rb = 0; rb < 4; rb++) {
        int mbase = mt*256 + (wv*4 + rb)*16 + q*4;
#pragma unroll
        for (int cb = 0; cb < 8; cb++) {
            int j = ntl*128 + cb*16 + c;
            float bv = bias[j];
#pragma unroll
            for (int reg = 0; reg < 4; reg++) {
                int m = mbase + reg;
                int tt = m & 127, nn = m >> 7;
                Op[(size_t)(tt*256 + nn)*1024 + j] = acc[rb][cb][reg] + bv;
            }
        }
    }
}

// ---------------------------------------------------------------------------
// One word-LSTM step via MFMA. Grid 256 = dir(2) x u0t(16) x nt(8).
// WG: 16 units x 4 gates x 32 seqs, K=256 in bf16 hi/lo (3-term MFMA).
// W image + h image staged via global_load_lds (16 B); all global reads
// (gates, mask, c, pooled) prefetched before the staging barrier so the
// post-MFMA epilogue is store-only.
__global__ __launch_bounds__(256) void word_step_mfma(
    const float* __restrict__ Gf, const float* __restrict__ Gb,
    const unsigned short* __restrict__ Wimg,
    const unsigned short* __restrict__ hin_img,
    unsigned short* __restrict__ hout_img,
    const int* __restrict__ mask,
    float* __restrict__ c_st, float* __restrict__ pooled, int t)
{
    extern __shared__ char ldsbuf[];
    unsigned short* Wl = (unsigned short*)ldsbuf;            // 69632 B
    unsigned short* Hl = Wl + 34816;                         // 36864 B
    float* gex = (float*)(ldsbuf + 69632 + 36864);           // [4][16][36] fp32

    const int tid = threadIdx.x;
    const int bid = blockIdx.x;
    const int dir = bid >> 7;
    const int u0t = (bid >> 3) & 15;
    const int nt  = bid & 7;
    const int te  = dir ? (127 - t) : t;
    const float* G = dir ? Gb : Gf;

    const int wv = tid >> 6, ln = tid & 63;
    const int c = ln & 15, q = ln >> 4;

    // ---- async stage W image (68 KB) + h image (36 KB) ----
    {
        const char* wsrc = (const char*)(Wimg + (size_t)(dir*16 + u0t) * 34816);
        const char* hsrc = (const char*)(hin_img + (size_t)(dir*8 + nt) * 18432);
        char* wdst = (char*)Wl;
        char* hdst = (char*)Hl;
#pragma unroll
        for (int j = 0; j < 17; j++) {
            int i = wv + 4*j;
            __builtin_amdgcn_global_load_lds(
                (const __attribute__((address_space(1))) unsigned int*)(wsrc + i*1024 + ln*16),
                (__attribute__((address_space(3))) unsigned int*)(wdst + i*1024), 16, 0, 0);
        }
#pragma unroll
        for (int j = 0; j < 9; j++) {
            int i = wv + 4*j;
            __builtin_amdgcn_global_load_lds(
                (const __attribute__((address_space(1))) unsigned int*)(hsrc + i*1024 + ln*16),
                (__attribute__((address_space(3))) unsigned int*)(hdst + i*1024), 16, 0, 0);
        }
    }

    // ---- epilogue prefetch (independent of staged data) ----
    const int uu = tid & 15;          // unit within tile
    const int np = tid >> 4;          // seq-pair
    const int uglob = u0t*16 + uu;
    const int n_a = nt*32 + np*2;     // first of 2 seqs
    float gpre[8]; int mk0, mk1; float cold0, cold1, pold0, pold1;
    {
        const float* Ga = G + (size_t)(te*256 + n_a)*1024 + uglob;
        const float* Gc = Ga + 1024;
#pragma unroll
        for (int g = 0; g < 4; g++) { gpre[g] = Ga[g*256]; gpre[4+g] = Gc[g*256]; }
        mk0 = mask[n_a*128 + te];
        mk1 = mask[(n_a + 1)*128 + te];
        cold0 = c_st[dir*65536 + n_a*256 + uglob];
        cold1 = c_st[dir*65536 + (n_a + 1)*256 + uglob];
        pold0 = pooled[n_a*512 + dir*256 + uglob];
        pold1 = pooled[(n_a + 1)*512 + dir*256 + uglob];
    }
    __syncthreads();   // waits vmcnt(0): staging complete

    // ---- MFMA: wave = gate wv; A rows = 16 units; B cols = 32 seqs (2 blocks) ----
    f32x4 acc[2];
    acc[0] = f32x4{0.f,0.f,0.f,0.f};
    acc[1] = f32x4{0.f,0.f,0.f,0.f};
#pragma unroll
    for (int kb = 0; kb < 8; kb++) {
        bf16x8 ahh = *(const bf16x8*)&Wl[(wv*16 + c)*264 + kb*32 + q*8];
        bf16x8 all_ = *(const bf16x8*)&Wl[16896 + (wv*16 + c)*264 + kb*32 + q*8];
#pragma unroll
        for (int sb = 0; sb < 2; sb++) {
            bf16x8 bh = *(const bf16x8*)&Hl[(sb*16 + c)*264 + kb*32 + q*8];
            bf16x8 bl = *(const bf16x8*)&Hl[8448 + (sb*16 + c)*264 + kb*32 + q*8];
            acc[sb] = __builtin_amdgcn_mfma_f32_16x16x32_bf16(ahh, bh, acc[sb], 0, 0, 0);
            acc[sb] = __builtin_amdgcn_mfma_f32_16x16x32_bf16(ahh, bl, acc[sb], 0, 0, 0);
            acc[sb] = __builtin_amdgcn_mfma_f32_16x16x32_bf16(all_, bh, acc[sb], 0, 0, 0);
        }
    }
    // write gates: row u=q*4+reg, col n=sb*16+c
#pragma unroll
    for (int sb = 0; sb < 2; sb++)
#pragma unroll
        for (int reg = 0; reg < 4; reg++)
            gex[(wv*16 + q*4 + reg)*36 + sb*16 + c] = acc[sb][reg];
    __syncthreads();

    // ---- cell update: thread handles (uu, n_a) and (uu, n_a+1); store-only ----
    unsigned short* hout = hout_img + (size_t)(dir*8 + nt) * 18432;
    {
        int nl = np*2;
        float iv = gex[(0*16 + uu)*36 + nl] + gpre[0];
        float fv = gex[(1*16 + uu)*36 + nl] + gpre[1];
        float gv = gex[(2*16 + uu)*36 + nl] + gpre[2];
        float ov = gex[(3*16 + uu)*36 + nl] + gpre[3];
        float cn = sigmoidf_(fv)*cold0 + sigmoidf_(iv)*tanhf(gv);
        float hn = sigmoidf_(ov)*tanhf(cn);
        c_st[dir*65536 + n_a*256 + uglob] = cn;
        unsigned short hh, hl; split_bf(hn, hh, hl);
        hout[nl*264 + uglob] = hh;
        hout[8448 + nl*264 + uglob] = hl;
        if (mk0) pooled[n_a*512 + dir*256 + uglob] = pold0 + hn;
    }
    {
        int nl = np*2 + 1;
        float iv = gex[(0*16 + uu)*36 + nl] + gpre[4];
        float fv = gex[(1*16 + uu)*36 + nl] + gpre[5];
        float gv = gex[(2*16 + uu)*36 + nl] + gpre[6];
        float ov = gex[(3*16 + uu)*36 + nl] + gpre[7];
        float cn = sigmoidf_(fv)*cold1 + sigmoidf_(iv)*tanhf(gv);
        float hn = sigmoidf_(ov)*tanhf(cn);
        c_st[dir*65536 + (n_a+1)*256 + uglob] = cn;
        unsigned short hh, hl; split_bf(hn, hh, hl);
        hout[nl*264 + uglob] = hh;
        hout[8448 + nl*264 + uglob] = hl;
        if (mk1) pooled[(n_a+1)*512 + dir*256 + uglob] = pold1 + hn;
    }
}

// ---------------------------------------------------------------------------
// fp32 input-projection GEMM (sentence level).
__global__ __launch_bounds__(256) void gemm_proj(
    const float* __restrict__ A, int M, int K,
    const float* __restrict__ Wf, const float* __restrict__ Wb,
    const float* __restrict__ bf, const float* __restrict__ bb,
    float* __restrict__ Of, float* __restrict__ Ob)
{
    __shared__ float As[16][132];
    __shared__ float Bs[16][132];
    const int t = threadIdx.x;
    const int n0 = blockIdx.x * 128;
    const int m0 = blockIdx.y * 128;
    const int sel = (n0 >= 1024);
    const float* Wp = sel ? Wb : Wf;
    const float* bp = sel ? bb : bf;
    float* Op = sel ? Ob : Of;
    const int n0d = n0 & 1023;
    const int tm = t >> 4;
    const int tn = t & 15;

    float acc[8][8];
#pragma unroll
    for (int i = 0; i < 8; i++)
#pragma unroll
        for (int j = 0; j < 8; j++) acc[i][j] = 0.f;

    for (int k0 = 0; k0 < K; k0 += 16) {
        __syncthreads();
#pragma unroll
        for (int rr = 0; rr < 2; rr++) {
            int idx = t + rr * 256;
            int row = idx >> 2, kq = idx & 3;
            float4 v = *(const float4*)&A[(size_t)(m0 + row) * K + k0 + kq * 4];
            As[kq*4+0][row] = v.x; As[kq*4+1][row] = v.y;
            As[kq*4+2][row] = v.z; As[kq*4+3][row] = v.w;
        }
#pragma unroll
        for (int rr = 0; rr < 2; rr++) {
            int idx = t + rr * 256;
            int row = idx >> 2, kq = idx & 3;
            float4 v = *(const float4*)&Wp[(size_t)(n0d + row) * K + k0 + kq * 4];
            Bs[kq*4+0][row] = v.x; Bs[kq*4+1][row] = v.y;
            Bs[kq*4+2][row] = v.z; Bs[kq*4+3][row] = v.w;
        }
        __syncthreads();
#pragma unroll
        for (int k = 0; k < 16; k++) {
            float4 a0 = *(const float4*)&As[k][tm*4];
            float4 a1 = *(const float4*)&As[k][tm*4+64];
            float4 b0 = *(const float4*)&Bs[k][tn*4];
            float4 b1 = *(const float4*)&Bs[k][tn*4+64];
            float av[8] = {a0.x,a0.y,a0.z,a0.w,a1.x,a1.y,a1.z,a1.w};
            float bv[8] = {b0.x,b0.y,b0.z,b0.w,b1.x,b1.y,b1.z,b1.w};
#pragma unroll
            for (int i = 0; i < 8; i++)
#pragma unroll
                for (int j = 0; j < 8; j++)
                    acc[i][j] += av[i] * bv[j];
        }
    }

#pragma unroll
    for (int ih = 0; ih < 2; ih++) {
#pragma unroll
        for (int i = 0; i < 4; i++) {
            int m = m0 + ih*64 + tm*4 + i;
#pragma unroll
            for (int jh = 0; jh < 2; jh++) {
                int col = n0d + jh*64 + tn*4;
                float4 bias4 = *(const float4*)&bp[col];
                float4 r;
                r.x = acc[ih*4+i][jh*4+0] + bias4.x;
                r.y = acc[ih*4+i][jh*4+1] + bias4.y;
                r.z = acc[ih*4+i][jh*4+2] + bias4.z;
                r.w = acc[ih*4+i][jh*4+3] + bias4.w;
                *(float4*)&Op[(size_t)m * 1024 + col] = r;
            }
        }
    }
}

// ---------------------------------------------------------------------------
__global__ __launch_bounds__(256) void pool_div(float* __restrict__ pooled,
                                                const int* __restrict__ mask) {
    __shared__ float red[256];
    int n = blockIdx.x, t = threadIdx.x;
    red[t] = (t < 128) ? (float)mask[n*128 + t] : 0.f;
    __syncthreads();
    for (int off = 128; off > 0; off >>= 1) {
        if (t < off) red[t] += red[t + off];
        __syncthreads();
    }
    float inv = 1.0f / fmaxf(red[0], 1.0f);
    pooled[n*512 + t] *= inv;
    pooled[n*512 + 256 + t] *= inv;
}

// ---------------------------------------------------------------------------
__global__ __launch_bounds__(256) void sent_step(
    const float* __restrict__ Gsf, const float* __restrict__ Gsb,
    const float* __restrict__ Wt,
    const float* __restrict__ h_in, float* __restrict__ h_out,
    float* __restrict__ c_s, float* __restrict__ final_h, int s)
{
    __shared__ float h_lds[256];
    __shared__ float part[256];
    __shared__ float ex[4][33];
    const int tid = threadIdx.x;
    const int bx = blockIdx.x;
    const int dir = bx >> 6;
    const int rb = bx & 63;
    const int b = rb >> 3;
    const int ut = rb & 7;
    const int u0 = ut * 32;
    const int t_eff = dir ? (31 - s) : s;
    const float* Gs = dir ? Gsb : Gsf;

    if (tid < 64) {
        float4 v = *(const float4*)&h_in[dir*2048 + b*256 + tid*4];
        *(float4*)&h_lds[tid*4] = v;
    }
    __syncthreads();

    const int kh = tid >> 7;
    const int rr = tid & 127;
    const int g = rr >> 5;
    const int uu = rr & 31;
    const int j = g*256 + u0 + uu;
    const float* wp = Wt + dir*262144 + kh*128*1024 + j;
    float acc = 0.f;
#pragma unroll 8
    for (int k = 0; k < 128; k++)
        acc += wp[k*1024] * h_lds[kh*128 + k];
    part[tid] = acc;
    __syncthreads();
    if (tid < 128) ex[g][uu] = part[tid] + part[tid + 128];
    __syncthreads();

    if (tid < 32) {
        int u = u0 + tid;
        size_t gb = (size_t)(b*32 + t_eff)*1024 + u;
        float iv = ex[0][tid] + Gs[gb];
        float fv = ex[1][tid] + Gs[gb + 256];
        float gv = ex[2][tid] + Gs[gb + 512];
        float ov = ex[3][tid] + Gs[gb + 768];
        int ci = dir*2048 + b*256 + u;
        float cold = c_s[ci];
        float cn = sigmoidf_(fv)*cold + sigmoidf_(iv)*tanhf(gv);
        float hn = sigmoidf_(ov)*tanhf(cn);
        c_s[ci] = cn;
        h_out[ci] = hn;
        if (t_eff == 31) final_h[b*512 + dir*256 + u] = hn;
    }
}

// ---------------------------------------------------------------------------
__global__ __launch_bounds__(256) void logits_k(const float* __restrict__ fh,
                                                const float* __restrict__ cw,
                                                const float* __restrict__ cb,
                                                float* __restrict__ out) {
    __shared__ float red[256];
    int tid = threadIdx.x;
    int o = tid >> 3;
    int b = o >> 2; int c = o & 3;
    int pp = tid & 7;
    float acc = 0.f;
    const float* fv = fh + b*512 + pp*64;
    const float* wv = cw + c*512 + pp*64;
#pragma unroll 8
    for (int e = 0; e < 64; e++) acc += fv[e]*wv[e];
    red[tid] = acc;
    __syncthreads();
    if (pp == 0) {
        float s = 0.f;
#pragma unroll
        for (int qq = 0; qq < 8; qq++) s += red[o*8 + qq];
        out[o] = s + cb[c];
    }
}

// ---------------------------------------------------------------------------
extern "C" void kernel_launch(void* const* d_in, const int* in_sizes, int n_in,
                              void* d_out, int out_size, void* d_ws, size_t ws_size,
                              hipStream_t stream) {
    const float* X       = (const float*)d_in[0];
    const int*   mask    = (const int*)d_in[1];
    const float* wl_ih_f = (const float*)d_in[2];
    const float* wl_hh_f = (const float*)d_in[3];
    const float* wl_b_f  = (const float*)d_in[4];
    const float* wl_ih_b = (const float*)d_in[5];
    const float* wl_hh_b = (const float*)d_in[6];
    const float* wl_b_b  = (const float*)d_in[7];
    const float* ws_ih_f = (const float*)d_in[8];
    const float* ws_hh_f = (const float*)d_in[9];
    const float* ws_b_f  = (const float*)d_in[10];
    const float* ws_ih_b = (const float*)d_in[11];
    const float* ws_hh_b = (const float*)d_in[12];
    const float* ws_b_b  = (const float*)d_in[13];
    const float* cls_w   = (const float*)d_in[14];
    const float* cls_b   = (const float*)d_in[15];
    float* out = (float*)d_out;
    float* w = (float*)d_ws;
    (void)in_sizes; (void)n_in; (void)out_size; (void)ws_size;

    // workspace layout (float offsets)
    float* Gf     = w;                         // 33,554,432  (t-major [t][n][1024])
    float* Gb     = Gf + 33554432;             // 33,554,432
    float* Gsf    = Gb + 33554432;             // 262,144
    float* Gsb    = Gsf + 262144;              // 262,144
    float* Wt     = Gsb + 262144;              // 524,288
    float* finalh = Wt + 524288;               // 4,096
    // ---- zero region (contiguous) ----
    float* c_st   = finalh + 4096;             // 131,072
    float* pooled = c_st + 131072;             // 131,072
    float* hs0    = pooled + 131072;           // 4,096
    float* hs1    = hs0 + 4096;                // 4,096
    float* cs     = hs1 + 4096;                // 4,096
    unsigned short* hA = (unsigned short*)(cs + 4096);  // 294,912 ushorts
    unsigned short* hB = hA + 294912;                   // 294,912
    // zero floats: 131072*2 + 4096*3 + 147456*2 = 569,344 -> 142,336 float4
    unsigned short* Xsw   = hB + 294912;                // 50,331,648 ushorts
    unsigned short* Wihsw = Xsw + 50331648;             // 3,145,728
    unsigned short* Wimg  = Wihsw + 3145728;            // 1,114,112

    zero_f4<<<556, 256, 0, stream>>>((float4*)c_st, 142336);
    prep_x<<<12288, 256, 0, stream>>>(X, Xsw);
    prep_wih_sw<<<768, 256, 0, stream>>>(wl_ih_f, wl_ih_b, Wihsw);
    prep_whh<<<2048, 256, 0, stream>>>(wl_hh_f, wl_hh_b, Wimg);
    transpose_whh<<<2048, 256, 0, stream>>>(ws_hh_f, ws_hh_b, Wt);

    // word input projection (split-bf16 MFMA, swizzled staging, t-major out)
    proj_mfma<<<dim3(16, 128), 256, 0, stream>>>(Xsw, Wihsw, wl_b_f, wl_b_b, Gf, Gb);

    // word recurrence: 128 per-step MFMA launches, h ping-pong bf16 hi/lo images
    hipFuncSetAttribute((const void*)word_step_mfma,
                        hipFuncAttributeMaxDynamicSharedMemorySize, 115712);
    for (int t = 0; t < 128; t++) {
        const unsigned short* hin = (t & 1) ? hB : hA;
        unsigned short* hout      = (t & 1) ? hA : hB;
        word_step_mfma<<<256, 256, 115712, stream>>>(Gf, Gb, Wimg, hin, hout,
                                                     mask, c_st, pooled, t);
    }

    pool_div<<<256, 256, 0, stream>>>(pooled, mask);

    // sentence input projection (fp32): (256x512) @ (512x2048)
    gemm_proj<<<dim3(16, 2), 256, 0, stream>>>(pooled, 256, 512,
                                               ws_ih_f, ws_ih_b, ws_b_f, ws_b_b,
                                               Gsf, Gsb);

    for (int s = 0; s < 32; s++) {
        float* hin  = (s & 1) ? hs1 : hs0;
        float* hout = (s & 1) ? hs0 : hs1;
        sent_step<<<128, 256, 0, stream>>>(Gsf, Gsb, Wt, hin, hout, cs, finalh, s);
    }

    logits_k<<<1, 256, 0, stream>>>(finalh, cls_w, cls_b, out);
}